// Round 14
// baseline (783.380 us; speedup 1.0000x reference)
//
#include <hip/hip_runtime.h>
#include <hip/hip_bf16.h>

#define DD 300
#define DP 320   // padded feature width

typedef unsigned short ushort_t;
typedef __attribute__((ext_vector_type(8))) short short8;
typedef __attribute__((ext_vector_type(4))) float f32x4;

__device__ __forceinline__ float b2f(ushort_t u) {
    unsigned x = ((unsigned)u) << 16;
    return __uint_as_float(x);
}
__device__ __forceinline__ ushort_t f2b(float f) {
    unsigned u = __float_as_uint(f);
    unsigned r = (u + 0x7FFFu + ((u >> 16) & 1u)) >> 16;
    return (ushort_t)r;
}

__device__ __forceinline__ void gload16(const void* g, void* l) {
    __builtin_amdgcn_global_load_lds((const __attribute__((address_space(1))) void*)g,
                                     (__attribute__((address_space(3))) void*)l, 16, 0, 0);
}

// ================= MFMA bf16 GEMM (2-phase double-buffered, round-12 proven) =================
template<int BNT, int BIAS, int RELU, int RESID, int RANK3>
__launch_bounds__(512)
__global__ void gemm_mfma(const ushort_t* __restrict__ A, int strideA, int M, int K,
                          const ushort_t* __restrict__ Bt,
                          const float* __restrict__ bias,
                          const ushort_t* __restrict__ resid,
                          const float* __restrict__ X3,
                          const float* __restrict__ W3,
                          int NCOL,
                          ushort_t* __restrict__ C, int strideC)
{
    constexpr int BM = 128, BK = 64, BN = 32 * BNT;
    constexpr int CA = BM * BK * 2 / 1024;
    constexpr int CB = BN * BK * 2 / 1024;
    constexpr int WCOLS = 16 * BNT;
    __shared__ ushort_t As[2][BM * BK];
    __shared__ ushort_t Bs[2][BN * BK];

    int bx = blockIdx.x, by = blockIdx.y;
    if (gridDim.x == 2 && (gridDim.y & 7) == 0) {
        int flat = bx + (by << 1);
        int xcd = flat & 7;
        int slot = flat >> 3;
        int rpx = gridDim.y >> 3;
        by = xcd * rpx + (slot >> 1);
        bx = slot & 1;
    }

    const int tid = threadIdx.x;
    const int lane = tid & 63, wid = tid >> 6;
    const int rowTile = by * BM;
    const int colTile = bx * BN;
    const int wm = wid >> 1, wn = wid & 1;

    const int lrow = lane >> 3;
    const int l8b = (lane & 7) * 16;

    f32x4 acc[2][BNT];
    #pragma unroll
    for (int f = 0; f < 2; ++f)
        #pragma unroll
        for (int q = 0; q < BNT; ++q) {
            f32x4 z = {0.f, 0.f, 0.f, 0.f};
            acc[f][q] = z;
        }

    auto stage = [&](int buf, int k0) {
        for (int c = wid; c < CA; c += 8) {
            int row = c * 8 + lrow;
            int colb = l8b ^ ((row & 7) << 4);
            int gr = rowTile + row; if (gr > M - 1) gr = M - 1;
            gload16(A + (size_t)gr * strideA + k0 + (colb >> 1), &As[buf][c * 512]);
        }
        for (int c = wid; c < CB; c += 8) {
            int row = c * 8 + lrow;
            int colb = l8b ^ ((row & 7) << 4);
            gload16(Bt + (size_t)(colTile + row) * K + k0 + (colb >> 1), &Bs[buf][c * 512]);
        }
    };

    auto compute = [&](int buf) {
        #pragma unroll
        for (int ks = 0; ks < 2; ++ks) {
            const int kidx = ks * 32 + (lane >> 4) * 8;
            short8 af[2], bf[BNT];
            #pragma unroll
            for (int f = 0; f < 2; ++f) {
                int row = wm * 32 + f * 16 + (lane & 15);
                int phys = (row * 128 + kidx * 2) ^ ((row & 7) << 4);
                af[f] = *(const short8*)((const char*)&As[buf][0] + phys);
            }
            #pragma unroll
            for (int q = 0; q < BNT; ++q) {
                int row = wn * WCOLS + q * 16 + (lane & 15);
                int phys = (row * 128 + kidx * 2) ^ ((row & 7) << 4);
                bf[q] = *(const short8*)((const char*)&Bs[buf][0] + phys);
            }
            #pragma unroll
            for (int f = 0; f < 2; ++f)
                #pragma unroll
                for (int q = 0; q < BNT; ++q)
                    acc[f][q] = __builtin_amdgcn_mfma_f32_16x16x32_bf16(af[f], bf[q], acc[f][q], 0, 0, 0);
        }
    };

    const int NT = K / BK;
    stage(0, 0);
    asm volatile("s_waitcnt vmcnt(0)" ::: "memory");
    __builtin_amdgcn_s_barrier();

    int cur = 0;
    for (int t = 0; t < NT - 1; ++t) {
        stage(cur ^ 1, (t + 1) * BK);
        compute(cur);
        asm volatile("s_waitcnt vmcnt(0)" ::: "memory");
        __builtin_amdgcn_s_barrier();
        cur ^= 1;
    }
    compute(cur);

    ushort_t* eb = &Bs[cur ^ 1][0] + wid * 16 * WCOLS;
    #pragma unroll
    for (int f = 0; f < 2; ++f) {
        #pragma unroll
        for (int q = 0; q < BNT; ++q) {
            #pragma unroll
            for (int r = 0; r < 4; ++r) {
                int rl = (lane >> 4) * 4 + r;
                int row = rowTile + wm * 32 + f * 16 + rl;
                int rr = row < M ? row : M - 1;
                int col = colTile + wn * WCOLS + q * 16 + (lane & 15);
                float v = acc[f][q][r];
                if (BIAS) v += bias[col];
                if (RANK3) {
                    if (col < NCOL) {
                        v += X3[rr * 3 + 0] * W3[col]
                           + X3[rr * 3 + 1] * W3[NCOL + col]
                           + X3[rr * 3 + 2] * W3[2 * NCOL + col];
                    }
                }
                if (RESID) v += b2f(resid[(size_t)rr * strideC + col]);
                if (RELU) v = fmaxf(v, 0.f);
                eb[rl * WCOLS + q * 16 + (lane & 15)] = f2b(v);
            }
        }
        for (int ch = lane; ch < 32 * BNT; ch += 64) {
            int rl = ch / (2 * BNT);
            int cc = ch - rl * (2 * BNT);
            int row = rowTile + wm * 32 + f * 16 + rl;
            if (row < M) {
                short8 vv = *(const short8*)(eb + rl * WCOLS + cc * 8);
                *(short8*)(C + (size_t)row * strideC + colTile + wn * WCOLS + cc * 8) = vv;
            }
        }
    }
}

// ================= fused layer kernel =================
// Per 64-row block: phase A: t = relu(agg@WG + bG + hin)  -> LDS tile T
//                   phase B: h' = t@WL + bL  (A-frags from T) -> T, hout
//                   phase C: u  = h'@WU + bU + x@fWp (rank3)   -> T, uout
// LDS: T 40KB (640B rows, 16B-slot XOR row&7) + Bst 20KB + Ast 4KB = 64KB
// -> 2 blocks/CU. BK=32 (64B staging rows, slot XOR row&3).
template<int HASC>
__launch_bounds__(512, 4)
__global__ void layer_fused(const ushort_t* __restrict__ agg,
                            const ushort_t* __restrict__ hin,
                            const ushort_t* __restrict__ WG, const float* __restrict__ bG,
                            const ushort_t* __restrict__ WL, const float* __restrict__ bL,
                            const ushort_t* __restrict__ WU, const float* __restrict__ bU,
                            const float* __restrict__ x, const float* __restrict__ fWn,
                            ushort_t* __restrict__ hout, ushort_t* __restrict__ uout,
                            int M)
{
    constexpr int BM = 64, BK = 32;
    __shared__ ushort_t T[BM * DP];      // 40 KB
    __shared__ ushort_t Bst[DP * BK];    // 20 KB
    __shared__ ushort_t Ast[BM * BK];    // 4 KB

    const int tid = threadIdx.x;
    const int lane = tid & 63, wid = tid >> 6;
    const int rowTile = blockIdx.x * BM;
    const int wm = wid >> 2, wn = wid & 3;      // 2 row-waves x 4 col-waves

    f32x4 acc[2][5];
    auto zacc = [&]() {
        #pragma unroll
        for (int f = 0; f < 2; ++f)
            #pragma unroll
            for (int q = 0; q < 5; ++q) {
                f32x4 z = {0.f, 0.f, 0.f, 0.f};
                acc[f][q] = z;
            }
    };

    auto stageB32 = [&](const ushort_t* W, int k0) {
        for (int c = wid; c < 20; c += 8) {
            int row = c * 16 + (lane >> 2);
            int cole = (((lane & 3) ^ (row & 3)) << 3);   // element offset
            gload16(W + (size_t)row * DP + k0 + cole, Bst + c * 512);
        }
    };
    auto stageA32 = [&](int k0) {
        for (int c = wid; c < 4; c += 8) {
            int row = c * 16 + (lane >> 2);
            int cole = (((lane & 3) ^ (row & 3)) << 3);
            int gr = rowTile + row; if (gr > M - 1) gr = M - 1;
            gload16(agg + (size_t)gr * DP + k0 + cole, Ast + c * 512);
        }
    };

    auto stepAB = [&]() {
        const int ks = lane >> 4;                 // k-slot 0..3
        short8 af[2], bf[5];
        #pragma unroll
        for (int f = 0; f < 2; ++f) {
            int row = wm * 32 + f * 16 + (lane & 15);
            af[f] = *(const short8*)((const char*)Ast + row * 64 + ((ks ^ (row & 3)) << 4));
        }
        #pragma unroll
        for (int q = 0; q < 5; ++q) {
            int row = wn * 80 + q * 16 + (lane & 15);
            bf[q] = *(const short8*)((const char*)Bst + row * 64 + ((ks ^ (row & 3)) << 4));
        }
        #pragma unroll
        for (int f = 0; f < 2; ++f)
            #pragma unroll
            for (int q = 0; q < 5; ++q)
                acc[f][q] = __builtin_amdgcn_mfma_f32_16x16x32_bf16(af[f], bf[q], acc[f][q], 0, 0, 0);
    };

    auto stepTB = [&](int k0) {
        const int ksl = lane >> 4;                // local slot 0..3
        const int ksg = (k0 >> 3) + ksl;          // global T slot 0..39
        short8 af[2], bf[5];
        #pragma unroll
        for (int f = 0; f < 2; ++f) {
            int row = wm * 32 + f * 16 + (lane & 15);
            af[f] = *(const short8*)((const char*)T + row * 640 + ((ksg ^ (row & 7)) << 4));
        }
        #pragma unroll
        for (int q = 0; q < 5; ++q) {
            int row = wn * 80 + q * 16 + (lane & 15);
            bf[q] = *(const short8*)((const char*)Bst + row * 64 + ((ksl ^ (row & 3)) << 4));
        }
        #pragma unroll
        for (int f = 0; f < 2; ++f)
            #pragma unroll
            for (int q = 0; q < 5; ++q)
                acc[f][q] = __builtin_amdgcn_mfma_f32_16x16x32_bf16(af[f], bf[q], acc[f][q], 0, 0, 0);
    };

    auto twrite = [&](int row, int col, float v) {
        *(ushort_t*)((char*)T + row * 640 + (((col >> 3) ^ (row & 7)) << 4) + ((col & 7) << 1)) = f2b(v);
    };

    auto copyOut = [&](ushort_t* out) {
        for (int ch = tid; ch < BM * 40; ch += 512) {
            int row = ch / 40, slot = ch - row * 40;
            int grow = rowTile + row;
            if (grow < M) {
                short8 v = *(const short8*)((const char*)T + row * 640 + ((slot ^ (row & 7)) << 4));
                *(short8*)(out + (size_t)grow * DP + slot * 8) = v;
            }
        }
    };

    // ---- phase A: t = relu(agg@WG + bG + hin) ----
    zacc();
    for (int t = 0; t < 10; ++t) {
        if (t) __builtin_amdgcn_s_barrier();
        stageA32(t * BK);
        stageB32(WG, t * BK);
        asm volatile("s_waitcnt vmcnt(0)" ::: "memory");
        __builtin_amdgcn_s_barrier();
        stepAB();
    }
    #pragma unroll
    for (int f = 0; f < 2; ++f)
        #pragma unroll
        for (int q = 0; q < 5; ++q)
            #pragma unroll
            for (int r = 0; r < 4; ++r) {
                int row = wm * 32 + f * 16 + (lane >> 4) * 4 + r;
                int grow = rowTile + row;
                int rr = grow < M ? grow : M - 1;
                int col = wn * 80 + q * 16 + (lane & 15);
                float v = acc[f][q][r] + bG[col] + b2f(hin[(size_t)rr * DP + col]);
                twrite(row, col, fmaxf(v, 0.f));
            }
    __builtin_amdgcn_s_barrier();                 // T = t complete

    // ---- phase B: h' = t@WL + bL ----
    zacc();
    for (int t = 0; t < 10; ++t) {
        if (t) __builtin_amdgcn_s_barrier();
        stageB32(WL, t * BK);
        asm volatile("s_waitcnt vmcnt(0)" ::: "memory");
        __builtin_amdgcn_s_barrier();
        stepTB(t * BK);
    }
    __builtin_amdgcn_s_barrier();                 // all done reading T(t)
    #pragma unroll
    for (int f = 0; f < 2; ++f)
        #pragma unroll
        for (int q = 0; q < 5; ++q)
            #pragma unroll
            for (int r = 0; r < 4; ++r) {
                int row = wm * 32 + f * 16 + (lane >> 4) * 4 + r;
                int col = wn * 80 + q * 16 + (lane & 15);
                twrite(row, col, acc[f][q][r] + bL[col]);
            }
    __builtin_amdgcn_s_barrier();                 // T = h' complete
    copyOut(hout);

    if (HASC) {
        // ---- phase C: u = h'@WU + bU + rank3 ----
        zacc();
        for (int t = 0; t < 10; ++t) {
            if (t) __builtin_amdgcn_s_barrier();
            stageB32(WU, t * BK);
            asm volatile("s_waitcnt vmcnt(0)" ::: "memory");
            __builtin_amdgcn_s_barrier();
            stepTB(t * BK);
        }
        __builtin_amdgcn_s_barrier();             // all done reading T(h')
        #pragma unroll
        for (int f = 0; f < 2; ++f)
            #pragma unroll
            for (int q = 0; q < 5; ++q)
                #pragma unroll
                for (int r = 0; r < 4; ++r) {
                    int row = wm * 32 + f * 16 + (lane >> 4) * 4 + r;
                    int grow = rowTile + row;
                    int rr = grow < M ? grow : M - 1;
                    int col = wn * 80 + q * 16 + (lane & 15);
                    float v = acc[f][q][r] + bU[col];
                    if (col < DD)
                        v += x[rr * 3 + 0] * fWn[col]
                           + x[rr * 3 + 1] * fWn[DD + col]
                           + x[rr * 3 + 2] * fWn[2 * DD + col];
                    twrite(row, col, v);
                }
        __builtin_amdgcn_s_barrier();
        copyOut(uout);
    }
}

// ============ single prep kernel: all weight transposes + padded biases ============
__global__ void prep(const float* __restrict__ pW2, const float* __restrict__ pW3,
                     const float* __restrict__ pb3,
                     const float* __restrict__ hW, const float* __restrict__ hb,
                     const float* __restrict__ fW,
                     const float* __restrict__ gW, const float* __restrict__ gb,
                     const float* __restrict__ lW, const float* __restrict__ lb,
                     ushort_t* __restrict__ WU, ushort_t* __restrict__ WG,
                     ushort_t* __restrict__ WL, ushort_t* __restrict__ W2,
                     ushort_t* __restrict__ W3e,
                     float* __restrict__ bU, float* __restrict__ bG,
                     float* __restrict__ bL, float* __restrict__ b3)
{
    const int SZ = DP * DP;
    int idx = blockIdx.x * 256 + threadIdx.x;
    if (idx < 3 * SZ) {
        int i = idx / SZ, r = idx - i * SZ;
        int n = r / DP, k = r - n * DP;
        float v = 0.f;
        if (k < DD) {
            if (n < DD) v = fW[i * 90900 + (3 + k) * DD + n];
            else if (n < DD + 3) v = hW[i * 900 + k * 3 + (n - DD)];
        }
        WU[idx] = f2b(v);
        return;
    }
    idx -= 3 * SZ;
    if (idx < 3 * SZ) {
        int i = idx / SZ, r = idx - i * SZ;
        int n = r / DP, k = r - n * DP;
        float v = (n < DD && k < DD) ? gW[i * 90000 + k * DD + n] : 0.f;
        WG[idx] = f2b(v);
        return;
    }
    idx -= 3 * SZ;
    if (idx < 3 * SZ) {
        int i = idx / SZ, r = idx - i * SZ;
        int n = r / DP, k = r - n * DP;
        float v = (n < DD && k < DD) ? lW[i * 90000 + k * DD + n] : 0.f;
        WL[idx] = f2b(v);
        return;
    }
    idx -= 3 * SZ;
    if (idx < 128 * 64) {
        int n = idx >> 6, k = idx & 63;
        W2[idx] = f2b(pW2[k * 128 + n]);
        return;
    }
    idx -= 128 * 64;
    if (idx < DP * 128) {
        int n = idx >> 7, k = idx & 127;
        W3e[idx] = f2b((n < DD) ? pW3[k * DD + n] : 0.f);
        return;
    }
    idx -= DP * 128;
    if (idx < 3 * DP) {
        int i = idx / DP, n = idx - i * DP;
        bU[idx] = (n >= DD && n < DD + 3) ? hb[i * 3 + (n - DD)] : 0.f;
        return;
    }
    idx -= 3 * DP;
    if (idx < 3 * DP) {
        int i = idx / DP, n = idx - i * DP;
        bG[idx] = (n < DD) ? gb[i * DD + n] : 0.f;
        return;
    }
    idx -= 3 * DP;
    if (idx < 3 * DP) {
        int i = idx / DP, n = idx - i * DP;
        bL[idx] = (n < DD) ? lb[i * DD + n] : 0.f;
        return;
    }
    idx -= 3 * DP;
    if (idx < DP) {
        b3[idx] = (idx < DD) ? pb3[idx] : 0.f;
        return;
    }
}

// ============ embed layer 1: h1 = relu(x @ pW1 + pb1), K=3 ============
__global__ void embed1(const float* __restrict__ x, const float* __restrict__ W,
                       const float* __restrict__ b, ushort_t* __restrict__ h1, int M)
{
    int idx = blockIdx.x * 256 + threadIdx.x;
    if (idx >= M * 64) return;
    int n = idx >> 6, c = idx & 63;
    const float* xr = x + n * 3;
    float v = xr[0] * W[c] + xr[1] * W[64 + c] + xr[2] * W[128 + c] + b[c];
    h1[idx] = f2b(fmaxf(v, 0.f));
}

// ============ CSR build ============
__global__ void hist_kernel(const int* __restrict__ dst, int* __restrict__ cnt, int E)
{
    int e = blockIdx.x * 256 + threadIdx.x;
    if (e < E) atomicAdd(&cnt[dst[e]], 1);
}
__global__ void scan1(const int* __restrict__ cnt, int* __restrict__ bsum, int N)
{
    __shared__ int s[256];
    int t = threadIdx.x;
    int i = blockIdx.x * 256 + t;
    s[t] = (i < N) ? cnt[i] : 0;
    __syncthreads();
    for (int o = 128; o > 0; o >>= 1) { if (t < o) s[t] += s[t + o]; __syncthreads(); }
    if (t == 0) bsum[blockIdx.x] = s[0];
}
__global__ void scan2(int* __restrict__ bsum, int nb)
{
    __shared__ int s[256];
    int t = threadIdx.x;
    int v = (t < nb) ? bsum[t] : 0;
    s[t] = v; __syncthreads();
    for (int o = 1; o < 256; o <<= 1) {
        int x = (t >= o) ? s[t - o] : 0;
        __syncthreads();
        s[t] += x;
        __syncthreads();
    }
    if (t < nb) bsum[t] = s[t] - v;
}
__global__ void scan3(const int* __restrict__ cnt, const int* __restrict__ bsumx,
                      int* __restrict__ off, int* __restrict__ cursor, int N)
{
    __shared__ int s[256];
    int t = threadIdx.x;
    int i = blockIdx.x * 256 + t;
    int v = (i < N) ? cnt[i] : 0;
    s[t] = v; __syncthreads();
    for (int o = 1; o < 256; o <<= 1) {
        int x = (t >= o) ? s[t - o] : 0;
        __syncthreads();
        s[t] += x;
        __syncthreads();
    }
    int excl = s[t] - v + bsumx[blockIdx.x];
    if (i <= N) {
        off[i] = excl;
        if (i < N) cursor[i] = excl;
    }
}
__global__ void scatter_kernel(const int* __restrict__ src, const int* __restrict__ dst,
                               int* __restrict__ cursor, int* __restrict__ csr, int E)
{
    int e = blockIdx.x * 256 + threadIdx.x;
    if (e < E) {
        int p = atomicAdd(&cursor[dst[e]], 1);
        csr[p] = src[e];
    }
}

// ============ segment max over CSR (proven version, 8/4/1 cascade) ============
__global__ void segmax(const ushort_t* __restrict__ u, const int* __restrict__ off,
                       const int* __restrict__ csr,
                       const float* __restrict__ x, const float* __restrict__ fWp,
                       const float* __restrict__ fb, ushort_t* __restrict__ agg, int Nn)
{
    int n = blockIdx.x * 4 + (threadIdx.x >> 6);
    int lane = threadIdx.x & 63;
    if (n >= Nn) return;
    const int e0 = off[n], e1 = off[n + 1];

    const ushort_t* un = u + (size_t)n * DP;
    float d0 = b2f(un[300]) - x[n * 3 + 0];
    float d1 = b2f(un[301]) - x[n * 3 + 1];
    float d2 = b2f(un[302]) - x[n * 3 + 2];

    float m[5];
    #pragma unroll
    for (int j = 0; j < 5; ++j) m[j] = -INFINITY;

    int e = e0;
    for (; e + 7 < e1; e += 8) {
        int s[8];
        #pragma unroll
        for (int q = 0; q < 8; ++q) s[q] = csr[e + q];
        #pragma unroll
        for (int q = 0; q < 8; ++q) {
            const ushort_t* r = u + (size_t)s[q] * DP + lane;
            #pragma unroll
            for (int j = 0; j < 5; ++j) m[j] = fmaxf(m[j], b2f(r[64 * j]));
        }
    }
    for (; e + 3 < e1; e += 4) {
        int s[4];
        #pragma unroll
        for (int q = 0; q < 4; ++q) s[q] = csr[e + q];
        #pragma unroll
        for (int q = 0; q < 4; ++q) {
            const ushort_t* r = u + (size_t)s[q] * DP + lane;
            #pragma unroll
            for (int j = 0; j < 5; ++j) m[j] = fmaxf(m[j], b2f(r[64 * j]));
        }
    }
    for (; e < e1; ++e) {
        const ushort_t* r = u + (size_t)csr[e] * DP + lane;
        #pragma unroll
        for (int j = 0; j < 5; ++j) m[j] = fmaxf(m[j], b2f(r[64 * j]));
    }

    #pragma unroll
    for (int j = 0; j < 5; ++j) {
        int col = lane + 64 * j;
        float o = 0.f;
        if (e1 > e0 && col < DD)
            o = m[j] + fb[col] + d0 * fWp[col] + d1 * fWp[DD + col] + d2 * fWp[2 * DD + col];
        agg[(size_t)n * DP + col] = f2b(o);
    }
}

// ============ global mean pool (bf16 h) ============
__global__ void pool_kernel(const ushort_t* __restrict__ h, const int* __restrict__ batch,
                            float* __restrict__ sums, float* __restrict__ cnts,
                            int Nn, int npb)
{
    int c = threadIdx.x;
    int n0 = blockIdx.x * npb;
    int n1 = min(n0 + npb, Nn);
    if (n0 >= n1) return;
    if (c < DD) {
        float run = 0.f;
        int g = batch[n0];
        for (int n = n0; n < n1; ++n) {
            int gn = batch[n];
            if (gn != g) { atomicAdd(&sums[g * DD + c], run); run = 0.f; g = gn; }
            run += b2f(h[(size_t)n * DP + c]);
        }
        atomicAdd(&sums[g * DD + c], run);
    } else if (c == DD) {
        float run = 0.f;
        int g = batch[n0];
        for (int n = n0; n < n1; ++n) {
            int gn = batch[n];
            if (gn != g) { atomicAdd(&cnts[g], run); run = 0.f; g = gn; }
            run += 1.f;
        }
        atomicAdd(&cnts[g], run);
    }
}

// ============ head: mean -> logits -> log_softmax ============
__global__ void head_kernel(const float* __restrict__ sums, const float* __restrict__ cnts,
                            const float* __restrict__ dW, const float* __restrict__ db,
                            float* __restrict__ out)
{
    __shared__ float mean[32][DD];
    __shared__ float logits[32][40];
    int tid = threadIdx.x;
    for (int i = tid; i < 32 * DD; i += 256) {
        int g = i / DD;
        mean[g][i - g * DD] = sums[i] / fmaxf(cnts[g], 1.f);
    }
    __syncthreads();
    for (int o = tid; o < 32 * 40; o += 256) {
        int g = o / 40, cls = o - g * 40;
        float acc = db[cls];
        for (int k = 0; k < DD; ++k) acc += mean[g][k] * dW[k * 40 + cls];
        logits[g][cls] = acc;
    }
    __syncthreads();
    if (tid < 32) {
        float mx = -INFINITY;
        #pragma unroll
        for (int j = 0; j < 40; ++j) mx = fmaxf(mx, logits[tid][j]);
        float se = 0.f;
        for (int j = 0; j < 40; ++j) se += expf(logits[tid][j] - mx);
        float lse = mx + logf(se);
        for (int j = 0; j < 40; ++j) out[tid * 40 + j] = logits[tid][j] - lse;
    }
}

extern "C" void kernel_launch(void* const* d_in, const int* in_sizes, int n_in,
                              void* d_out, int out_size, void* d_ws, size_t ws_size,
                              hipStream_t stream)
{
    const float* x     = (const float*)d_in[0];
    const int*   ei    = (const int*)d_in[1];
    const int*   batch = (const int*)d_in[2];
    const float* pW1   = (const float*)d_in[3];
    const float* pb1   = (const float*)d_in[4];
    const float* pW2   = (const float*)d_in[5];
    const float* pb2   = (const float*)d_in[6];
    const float* pW3   = (const float*)d_in[7];
    const float* pb3   = (const float*)d_in[8];
    const float* hW    = (const float*)d_in[9];
    const float* hb    = (const float*)d_in[10];
    const float* fW    = (const float*)d_in[11];
    const float* fb    = (const float*)d_in[12];
    const float* gW    = (const float*)d_in[13];
    const float* gb    = (const float*)d_in[14];
    const float* lW    = (const float*)d_in[15];
    const float* lb    = (const float*)d_in[16];
    const float* dW    = (const float*)d_in[17];
    const float* db    = (const float*)d_in[18];

    const int N = in_sizes[0] / 3;
    const int E = in_sizes[1] / 2;
    const int G = 32;
    const int SZ = DP * DP;
    (void)ws_size; (void)n_in; (void)out_size;

    char* wsb = (char*)d_ws;
    size_t offb = 0;
    auto alloc = [&](size_t bytes) {
        void* p = wsb + offb;
        offb += (bytes + 255) & ~(size_t)255;
        return p;
    };
    ushort_t* h    = (ushort_t*)alloc((size_t)N * DP * 2);
    ushort_t* u    = (ushort_t*)alloc((size_t)N * DP * 2);
    ushort_t* agg  = (ushort_t*)alloc((size_t)N * DP * 2);
    ushort_t* h1   = (ushort_t*)alloc((size_t)N * 64 * 2);
    ushort_t* h2   = (ushort_t*)alloc((size_t)N * 128 * 2);
    ushort_t* WU   = (ushort_t*)alloc((size_t)3 * SZ * 2);
    ushort_t* WG   = (ushort_t*)alloc((size_t)3 * SZ * 2);
    ushort_t* WL   = (ushort_t*)alloc((size_t)3 * SZ * 2);
    ushort_t* W2   = (ushort_t*)alloc((size_t)128 * 64 * 2);
    ushort_t* W3e  = (ushort_t*)alloc((size_t)DP * 128 * 2);
    float*    bU   = (float*)alloc((size_t)3 * DP * 4);
    float*    bG   = (float*)alloc((size_t)3 * DP * 4);
    float*    bL   = (float*)alloc((size_t)3 * DP * 4);
    float*    b3   = (float*)alloc((size_t)DP * 4);
    int*      cnt    = (int*)alloc((size_t)(N + 1) * 4);
    int*      offp   = (int*)alloc((size_t)(N + 1) * 4);
    int*      cursor = (int*)alloc((size_t)N * 4);
    int*      bsum   = (int*)alloc((size_t)256 * 4);
    int*      csr    = (int*)alloc((size_t)E * 4);
    float*    sums   = (float*)alloc((size_t)(G * DD + G) * 4);
    float*    cnts   = sums + G * DD;

    const int* srcp = ei;
    const int* dstp = ei + E;
    const int nb = (N + 255) / 256;
    const dim3 blk(256);
    const int rowBlocks = (N + 127) / 128;               // 391
    const int rowBlocksPad = ((rowBlocks + 7) / 8) * 8;  // 392
    const int fuseBlocks = (N + 63) / 64;                // 782

    // ---- prep ----
    const int prepTotal = 3 * SZ * 3 + 128 * 64 + DP * 128 + 3 * DP * 3 + DP;
    prep<<<dim3((prepTotal + 255) / 256), blk, 0, stream>>>(
        pW2, pW3, pb3, hW, hb, fW, gW, gb, lW, lb,
        WU, WG, WL, W2, W3e, bU, bG, bL, b3);

    // ---- CSR build ----
    hipMemsetAsync(cnt, 0, (size_t)(N + 1) * 4, stream);
    hist_kernel<<<dim3((E + 255) / 256), blk, 0, stream>>>(dstp, cnt, E);
    scan1<<<dim3(nb), blk, 0, stream>>>(cnt, bsum, N);
    scan2<<<dim3(1), blk, 0, stream>>>(bsum, nb);
    scan3<<<dim3(nb), blk, 0, stream>>>(cnt, bsum, offp, cursor, N);
    scatter_kernel<<<dim3((E + 255) / 256), blk, 0, stream>>>(srcp, dstp, cursor, csr, E);

    // ---- embed MLP ----
    embed1<<<dim3((N * 64 + 255) / 256), blk, 0, stream>>>(x, pW1, pb1, h1, N);
    gemm_mfma<4, 1, 1, 0, 0><<<dim3(1, rowBlocks), dim3(512), 0, stream>>>(
        h1, 64, N, 64, W2, pb2, nullptr, nullptr, nullptr, 128, h2, 128);
    gemm_mfma<5, 1, 0, 0, 0><<<dim3(2, rowBlocksPad), dim3(512), 0, stream>>>(
        h2, 128, N, 128, W3e, b3, nullptr, nullptr, nullptr, DD, h, DP);

    // ---- u1 = h @ fWh0 + x @ fWp0 (+ delta cols) ----
    gemm_mfma<5, 1, 0, 0, 1><<<dim3(2, rowBlocksPad), dim3(512), 0, stream>>>(
        h, DP, N, DP, WU, bU, nullptr, x, fW, DD, u, DP);

    // ---- 3 PointGNNConv layers (segmax + fused g/l/u-next) ----
    for (int i = 0; i < 3; ++i) {
        const float* fWi = fW + (size_t)i * 90900;
        const float* fbi = fb + (size_t)i * DD;

        segmax<<<dim3((N + 3) / 4), blk, 0, stream>>>(u, offp, csr, x, fWi, fbi, agg, N);

        if (i < 2) {
            layer_fused<1><<<dim3(fuseBlocks), dim3(512), 0, stream>>>(
                agg, h,
                WG + (size_t)i * SZ, bG + (size_t)i * DP,
                WL + (size_t)i * SZ, bL + (size_t)i * DP,
                WU + (size_t)(i + 1) * SZ, bU + (size_t)(i + 1) * DP,
                x, fW + (size_t)(i + 1) * 90900,
                h, u, N);
        } else {
            layer_fused<0><<<dim3(fuseBlocks), dim3(512), 0, stream>>>(
                agg, h,
                WG + (size_t)i * SZ, bG + (size_t)i * DP,
                WL + (size_t)i * SZ, bL + (size_t)i * DP,
                nullptr, nullptr, nullptr, nullptr,
                h, nullptr, N);
        }
    }

    // ---- global mean pool + head ----
    hipMemsetAsync(sums, 0, (size_t)(G * DD + G) * 4, stream);
    pool_kernel<<<dim3((N + 127) / 128), dim3(320), 0, stream>>>(h, batch, sums, cnts, N, 128);
    head_kernel<<<dim3(1), dim3(256), 0, stream>>>(sums, cnts, dW, db, (float*)d_out);
}

// Round 15
// 666.318 us; speedup vs baseline: 1.1757x; 1.1757x over previous
//
#include <hip/hip_runtime.h>
#include <hip/hip_bf16.h>

#define DD 300
#define DP 320   // padded feature width

typedef unsigned short ushort_t;
typedef __attribute__((ext_vector_type(8))) short short8;
typedef __attribute__((ext_vector_type(4))) float f32x4;

__device__ __forceinline__ float b2f(ushort_t u) {
    unsigned x = ((unsigned)u) << 16;
    return __uint_as_float(x);
}
__device__ __forceinline__ ushort_t f2b(float f) {
    unsigned u = __float_as_uint(f);
    unsigned r = (u + 0x7FFFu + ((u >> 16) & 1u)) >> 16;
    return (ushort_t)r;
}

__device__ __forceinline__ void gload16(const void* g, void* l) {
    __builtin_amdgcn_global_load_lds((const __attribute__((address_space(1))) void*)g,
                                     (__attribute__((address_space(3))) void*)l, 16, 0, 0);
}

// ================= MFMA bf16 GEMM (2-phase double-buffered) =================
// C[M][·] = A[M][K](bf16) @ Bt^T ; Bt is [Np][K] bf16 pre-transposed/padded.
// BM=128, BK=64, BN=32*BNT, 512 threads = 8 waves (4 row-waves x 2 col-waves).
// T3 minimum 2-phase: stage(next) issued BEFORE compute(cur); raw s_barrier
// with explicit vmcnt(0) so next-tile loads fly under current-tile MFMA.
// XCD swizzle: when gridX==2 and gridY%8==0, remap so both col-tiles of a
// row-panel run consecutively on the SAME XCD (A-panel L2 reuse).
template<int BNT, int BIAS, int RELU, int RESID, int RANK3>
__launch_bounds__(512)
__global__ void gemm_mfma(const ushort_t* __restrict__ A, int strideA, int M, int K,
                          const ushort_t* __restrict__ Bt,
                          const float* __restrict__ bias,
                          const ushort_t* __restrict__ resid,
                          const float* __restrict__ X3,
                          const float* __restrict__ W3,
                          int NCOL,
                          ushort_t* __restrict__ C, int strideC)
{
    constexpr int BM = 128, BK = 64, BN = 32 * BNT;
    constexpr int CA = BM * BK * 2 / 1024;
    constexpr int CB = BN * BK * 2 / 1024;
    constexpr int WCOLS = 16 * BNT;          // cols per wave
    __shared__ ushort_t As[2][BM * BK];
    __shared__ ushort_t Bs[2][BN * BK];

    int bx = blockIdx.x, by = blockIdx.y;
    if (gridDim.x == 2 && (gridDim.y & 7) == 0) {
        int flat = bx + (by << 1);           // HW linear id (x fastest)
        int xcd = flat & 7;                  // round-robin XCD map
        int slot = flat >> 3;
        int rpx = gridDim.y >> 3;            // row-panels per XCD
        by = xcd * rpx + (slot >> 1);
        bx = slot & 1;
    }

    const int tid = threadIdx.x;
    const int lane = tid & 63, wid = tid >> 6;
    const int rowTile = by * BM;
    const int colTile = bx * BN;
    const int wm = wid >> 1, wn = wid & 1;

    const int lrow = lane >> 3;
    const int l8b = (lane & 7) * 16;

    f32x4 acc[2][BNT];
    #pragma unroll
    for (int f = 0; f < 2; ++f)
        #pragma unroll
        for (int q = 0; q < BNT; ++q) {
            f32x4 z = {0.f, 0.f, 0.f, 0.f};
            acc[f][q] = z;
        }

    auto stage = [&](int buf, int k0) {
        for (int c = wid; c < CA; c += 8) {
            int row = c * 8 + lrow;
            int colb = l8b ^ ((row & 7) << 4);
            int gr = rowTile + row; if (gr > M - 1) gr = M - 1;
            gload16(A + (size_t)gr * strideA + k0 + (colb >> 1), &As[buf][c * 512]);
        }
        for (int c = wid; c < CB; c += 8) {
            int row = c * 8 + lrow;
            int colb = l8b ^ ((row & 7) << 4);
            gload16(Bt + (size_t)(colTile + row) * K + k0 + (colb >> 1), &Bs[buf][c * 512]);
        }
    };

    auto compute = [&](int buf) {
        #pragma unroll
        for (int ks = 0; ks < 2; ++ks) {
            const int kidx = ks * 32 + (lane >> 4) * 8;
            short8 af[2], bf[BNT];
            #pragma unroll
            for (int f = 0; f < 2; ++f) {
                int row = wm * 32 + f * 16 + (lane & 15);
                int phys = (row * 128 + kidx * 2) ^ ((row & 7) << 4);
                af[f] = *(const short8*)((const char*)&As[buf][0] + phys);
            }
            #pragma unroll
            for (int q = 0; q < BNT; ++q) {
                int row = wn * WCOLS + q * 16 + (lane & 15);
                int phys = (row * 128 + kidx * 2) ^ ((row & 7) << 4);
                bf[q] = *(const short8*)((const char*)&Bs[buf][0] + phys);
            }
            #pragma unroll
            for (int f = 0; f < 2; ++f)
                #pragma unroll
                for (int q = 0; q < BNT; ++q)
                    acc[f][q] = __builtin_amdgcn_mfma_f32_16x16x32_bf16(af[f], bf[q], acc[f][q], 0, 0, 0);
        }
    };

    const int NT = K / BK;                   // K is a multiple of 64 here
    stage(0, 0);
    asm volatile("s_waitcnt vmcnt(0)" ::: "memory");
    __builtin_amdgcn_s_barrier();

    int cur = 0;
    for (int t = 0; t < NT - 1; ++t) {
        stage(cur ^ 1, (t + 1) * BK);        // prefetch next tile (in flight)
        compute(cur);                        // MFMA on current tile
        asm volatile("s_waitcnt vmcnt(0)" ::: "memory");
        __builtin_amdgcn_s_barrier();
        cur ^= 1;
    }
    compute(cur);                            // last tile (no prefetch)

    // ---- epilogue: per-wave private LDS slice in the idle buffer ----
    ushort_t* eb = &Bs[cur ^ 1][0] + wid * 16 * WCOLS;
    #pragma unroll
    for (int f = 0; f < 2; ++f) {
        #pragma unroll
        for (int q = 0; q < BNT; ++q) {
            #pragma unroll
            for (int r = 0; r < 4; ++r) {
                int rl = (lane >> 4) * 4 + r;
                int row = rowTile + wm * 32 + f * 16 + rl;
                int rr = row < M ? row : M - 1;          // clamp for side reads
                int col = colTile + wn * WCOLS + q * 16 + (lane & 15);
                float v = acc[f][q][r];
                if (BIAS) v += bias[col];
                if (RANK3) {
                    if (col < NCOL) {
                        v += X3[rr * 3 + 0] * W3[col]
                           + X3[rr * 3 + 1] * W3[NCOL + col]
                           + X3[rr * 3 + 2] * W3[2 * NCOL + col];
                    }
                }
                if (RESID) v += b2f(resid[(size_t)rr * strideC + col]);
                if (RELU) v = fmaxf(v, 0.f);
                eb[rl * WCOLS + q * 16 + (lane & 15)] = f2b(v);
            }
        }
        for (int ch = lane; ch < 32 * BNT; ch += 64) {
            int rl = ch / (2 * BNT);
            int cc = ch - rl * (2 * BNT);
            int row = rowTile + wm * 32 + f * 16 + rl;
            if (row < M) {
                short8 vv = *(const short8*)(eb + rl * WCOLS + cc * 8);
                *(short8*)(C + (size_t)row * strideC + colTile + wn * WCOLS + cc * 8) = vv;
            }
        }
    }
}

// ============ single prep kernel: all weight transposes + padded biases ============
__global__ void prep(const float* __restrict__ pW2, const float* __restrict__ pW3,
                     const float* __restrict__ pb3,
                     const float* __restrict__ hW, const float* __restrict__ hb,
                     const float* __restrict__ fW,
                     const float* __restrict__ gW, const float* __restrict__ gb,
                     const float* __restrict__ lW, const float* __restrict__ lb,
                     ushort_t* __restrict__ WU, ushort_t* __restrict__ WG,
                     ushort_t* __restrict__ WL, ushort_t* __restrict__ W2,
                     ushort_t* __restrict__ W3e,
                     float* __restrict__ bU, float* __restrict__ bG,
                     float* __restrict__ bL, float* __restrict__ b3)
{
    const int SZ = DP * DP;
    int idx = blockIdx.x * 256 + threadIdx.x;
    if (idx < 3 * SZ) {
        int i = idx / SZ, r = idx - i * SZ;
        int n = r / DP, k = r - n * DP;
        float v = 0.f;
        if (k < DD) {
            if (n < DD) v = fW[i * 90900 + (3 + k) * DD + n];
            else if (n < DD + 3) v = hW[i * 900 + k * 3 + (n - DD)];
        }
        WU[idx] = f2b(v);
        return;
    }
    idx -= 3 * SZ;
    if (idx < 3 * SZ) {
        int i = idx / SZ, r = idx - i * SZ;
        int n = r / DP, k = r - n * DP;
        float v = (n < DD && k < DD) ? gW[i * 90000 + k * DD + n] : 0.f;
        WG[idx] = f2b(v);
        return;
    }
    idx -= 3 * SZ;
    if (idx < 3 * SZ) {
        int i = idx / SZ, r = idx - i * SZ;
        int n = r / DP, k = r - n * DP;
        float v = (n < DD && k < DD) ? lW[i * 90000 + k * DD + n] : 0.f;
        WL[idx] = f2b(v);
        return;
    }
    idx -= 3 * SZ;
    if (idx < 128 * 64) {
        int n = idx >> 6, k = idx & 63;
        W2[idx] = f2b(pW2[k * 128 + n]);
        return;
    }
    idx -= 128 * 64;
    if (idx < DP * 128) {
        int n = idx >> 7, k = idx & 127;
        W3e[idx] = f2b((n < DD) ? pW3[k * DD + n] : 0.f);
        return;
    }
    idx -= DP * 128;
    if (idx < 3 * DP) {
        int i = idx / DP, n = idx - i * DP;
        bU[idx] = (n >= DD && n < DD + 3) ? hb[i * 3 + (n - DD)] : 0.f;
        return;
    }
    idx -= 3 * DP;
    if (idx < 3 * DP) {
        int i = idx / DP, n = idx - i * DP;
        bG[idx] = (n < DD) ? gb[i * DD + n] : 0.f;
        return;
    }
    idx -= 3 * DP;
    if (idx < 3 * DP) {
        int i = idx / DP, n = idx - i * DP;
        bL[idx] = (n < DD) ? lb[i * DD + n] : 0.f;
        return;
    }
    idx -= 3 * DP;
    if (idx < DP) {
        b3[idx] = (idx < DD) ? pb3[idx] : 0.f;
        return;
    }
}

// ============ embed layer 1: h1 = relu(x @ pW1 + pb1), K=3 ============
__global__ void embed1(const float* __restrict__ x, const float* __restrict__ W,
                       const float* __restrict__ b, ushort_t* __restrict__ h1, int M)
{
    int idx = blockIdx.x * 256 + threadIdx.x;
    if (idx >= M * 64) return;
    int n = idx >> 6, c = idx & 63;
    const float* xr = x + n * 3;
    float v = xr[0] * W[c] + xr[1] * W[64 + c] + xr[2] * W[128 + c] + b[c];
    h1[idx] = f2b(fmaxf(v, 0.f));
}

// ============ CSR build ============
__global__ void hist_kernel(const int* __restrict__ dst, int* __restrict__ cnt, int E)
{
    int e = blockIdx.x * 256 + threadIdx.x;
    if (e < E) atomicAdd(&cnt[dst[e]], 1);
}
__global__ void scan1(const int* __restrict__ cnt, int* __restrict__ bsum, int N)
{
    __shared__ int s[256];
    int t = threadIdx.x;
    int i = blockIdx.x * 256 + t;
    s[t] = (i < N) ? cnt[i] : 0;
    __syncthreads();
    for (int o = 128; o > 0; o >>= 1) { if (t < o) s[t] += s[t + o]; __syncthreads(); }
    if (t == 0) bsum[blockIdx.x] = s[0];
}
__global__ void scan2(int* __restrict__ bsum, int nb)
{
    __shared__ int s[256];
    int t = threadIdx.x;
    int v = (t < nb) ? bsum[t] : 0;
    s[t] = v; __syncthreads();
    for (int o = 1; o < 256; o <<= 1) {
        int x = (t >= o) ? s[t - o] : 0;
        __syncthreads();
        s[t] += x;
        __syncthreads();
    }
    if (t < nb) bsum[t] = s[t] - v;
}
__global__ void scan3(const int* __restrict__ cnt, const int* __restrict__ bsumx,
                      int* __restrict__ off, int* __restrict__ cursor, int N)
{
    __shared__ int s[256];
    int t = threadIdx.x;
    int i = blockIdx.x * 256 + t;
    int v = (i < N) ? cnt[i] : 0;
    s[t] = v; __syncthreads();
    for (int o = 1; o < 256; o <<= 1) {
        int x = (t >= o) ? s[t - o] : 0;
        __syncthreads();
        s[t] += x;
        __syncthreads();
    }
    int excl = s[t] - v + bsumx[blockIdx.x];
    if (i <= N) {
        off[i] = excl;
        if (i < N) cursor[i] = excl;
    }
}
__global__ void scatter_kernel(const int* __restrict__ src, const int* __restrict__ dst,
                               int* __restrict__ cursor, int* __restrict__ csr, int E)
{
    int e = blockIdx.x * 256 + threadIdx.x;
    if (e < E) {
        int p = atomicAdd(&cursor[dst[e]], 1);
        csr[p] = src[e];
    }
}

// ============ segment max over CSR ============
// All 64 lanes active, scalar coalesced 2B loads; 8/4/1 unroll cascade.
// delta comes from u[n][300..302] (fused into the u-GEMM).
__global__ void segmax(const ushort_t* __restrict__ u, const int* __restrict__ off,
                       const int* __restrict__ csr,
                       const float* __restrict__ x, const float* __restrict__ fWp,
                       const float* __restrict__ fb, ushort_t* __restrict__ agg, int Nn)
{
    int n = blockIdx.x * 4 + (threadIdx.x >> 6);
    int lane = threadIdx.x & 63;
    if (n >= Nn) return;
    const int e0 = off[n], e1 = off[n + 1];

    const ushort_t* un = u + (size_t)n * DP;
    float d0 = b2f(un[300]) - x[n * 3 + 0];
    float d1 = b2f(un[301]) - x[n * 3 + 1];
    float d2 = b2f(un[302]) - x[n * 3 + 2];

    float m[5];
    #pragma unroll
    for (int j = 0; j < 5; ++j) m[j] = -INFINITY;

    int e = e0;
    for (; e + 7 < e1; e += 8) {
        int s[8];
        #pragma unroll
        for (int q = 0; q < 8; ++q) s[q] = csr[e + q];
        #pragma unroll
        for (int q = 0; q < 8; ++q) {
            const ushort_t* r = u + (size_t)s[q] * DP + lane;
            #pragma unroll
            for (int j = 0; j < 5; ++j) m[j] = fmaxf(m[j], b2f(r[64 * j]));
        }
    }
    for (; e + 3 < e1; e += 4) {
        int s[4];
        #pragma unroll
        for (int q = 0; q < 4; ++q) s[q] = csr[e + q];
        #pragma unroll
        for (int q = 0; q < 4; ++q) {
            const ushort_t* r = u + (size_t)s[q] * DP + lane;
            #pragma unroll
            for (int j = 0; j < 5; ++j) m[j] = fmaxf(m[j], b2f(r[64 * j]));
        }
    }
    for (; e < e1; ++e) {
        const ushort_t* r = u + (size_t)csr[e] * DP + lane;
        #pragma unroll
        for (int j = 0; j < 5; ++j) m[j] = fmaxf(m[j], b2f(r[64 * j]));
    }

    #pragma unroll
    for (int j = 0; j < 5; ++j) {
        int col = lane + 64 * j;
        float o = 0.f;
        if (e1 > e0 && col < DD)
            o = m[j] + fb[col] + d0 * fWp[col] + d1 * fWp[DD + col] + d2 * fWp[2 * DD + col];
        agg[(size_t)n * DP + col] = f2b(o);
    }
}

// ============ global mean pool (bf16 h) ============
__global__ void pool_kernel(const ushort_t* __restrict__ h, const int* __restrict__ batch,
                            float* __restrict__ sums, float* __restrict__ cnts,
                            int Nn, int npb)
{
    int c = threadIdx.x;
    int n0 = blockIdx.x * npb;
    int n1 = min(n0 + npb, Nn);
    if (n0 >= n1) return;
    if (c < DD) {
        float run = 0.f;
        int g = batch[n0];
        for (int n = n0; n < n1; ++n) {
            int gn = batch[n];
            if (gn != g) { atomicAdd(&sums[g * DD + c], run); run = 0.f; g = gn; }
            run += b2f(h[(size_t)n * DP + c]);
        }
        atomicAdd(&sums[g * DD + c], run);
    } else if (c == DD) {
        float run = 0.f;
        int g = batch[n0];
        for (int n = n0; n < n1; ++n) {
            int gn = batch[n];
            if (gn != g) { atomicAdd(&cnts[g], run); run = 0.f; g = gn; }
            run += 1.f;
        }
        atomicAdd(&cnts[g], run);
    }
}

// ============ head: mean -> logits -> log_softmax ============
__global__ void head_kernel(const float* __restrict__ sums, const float* __restrict__ cnts,
                            const float* __restrict__ dW, const float* __restrict__ db,
                            float* __restrict__ out)
{
    __shared__ float mean[32][DD];
    __shared__ float logits[32][40];
    int tid = threadIdx.x;
    for (int i = tid; i < 32 * DD; i += 256) {
        int g = i / DD;
        mean[g][i - g * DD] = sums[i] / fmaxf(cnts[g], 1.f);
    }
    __syncthreads();
    for (int o = tid; o < 32 * 40; o += 256) {
        int g = o / 40, cls = o - g * 40;
        float acc = db[cls];
        for (int k = 0; k < DD; ++k) acc += mean[g][k] * dW[k * 40 + cls];
        logits[g][cls] = acc;
    }
    __syncthreads();
    if (tid < 32) {
        float mx = -INFINITY;
        #pragma unroll
        for (int j = 0; j < 40; ++j) mx = fmaxf(mx, logits[tid][j]);
        float se = 0.f;
        for (int j = 0; j < 40; ++j) se += expf(logits[tid][j] - mx);
        float lse = mx + logf(se);
        for (int j = 0; j < 40; ++j) out[tid * 40 + j] = logits[tid][j] - lse;
    }
}

extern "C" void kernel_launch(void* const* d_in, const int* in_sizes, int n_in,
                              void* d_out, int out_size, void* d_ws, size_t ws_size,
                              hipStream_t stream)
{
    const float* x     = (const float*)d_in[0];
    const int*   ei    = (const int*)d_in[1];
    const int*   batch = (const int*)d_in[2];
    const float* pW1   = (const float*)d_in[3];
    const float* pb1   = (const float*)d_in[4];
    const float* pW2   = (const float*)d_in[5];
    const float* pb2   = (const float*)d_in[6];
    const float* pW3   = (const float*)d_in[7];
    const float* pb3   = (const float*)d_in[8];
    const float* hW    = (const float*)d_in[9];
    const float* hb    = (const float*)d_in[10];
    const float* fW    = (const float*)d_in[11];
    const float* fb    = (const float*)d_in[12];
    const float* gW    = (const float*)d_in[13];
    const float* gb    = (const float*)d_in[14];
    const float* lW    = (const float*)d_in[15];
    const float* lb    = (const float*)d_in[16];
    const float* dW    = (const float*)d_in[17];
    const float* db    = (const float*)d_in[18];

    const int N = in_sizes[0] / 3;
    const int E = in_sizes[1] / 2;
    const int G = 32;
    const int SZ = DP * DP;
    (void)ws_size; (void)n_in; (void)out_size;

    char* wsb = (char*)d_ws;
    size_t offb = 0;
    auto alloc = [&](size_t bytes) {
        void* p = wsb + offb;
        offb += (bytes + 255) & ~(size_t)255;
        return p;
    };
    ushort_t* h    = (ushort_t*)alloc((size_t)N * DP * 2);
    ushort_t* u    = (ushort_t*)alloc((size_t)N * DP * 2);
    ushort_t* agg  = (ushort_t*)alloc((size_t)N * DP * 2);
    ushort_t* h1   = (ushort_t*)alloc((size_t)N * 64 * 2);
    ushort_t* h2   = (ushort_t*)alloc((size_t)N * 128 * 2);
    ushort_t* WU   = (ushort_t*)alloc((size_t)3 * SZ * 2);
    ushort_t* WG   = (ushort_t*)alloc((size_t)3 * SZ * 2);
    ushort_t* WL   = (ushort_t*)alloc((size_t)3 * SZ * 2);
    ushort_t* W2   = (ushort_t*)alloc((size_t)128 * 64 * 2);
    ushort_t* W3e  = (ushort_t*)alloc((size_t)DP * 128 * 2);
    float*    bU   = (float*)alloc((size_t)3 * DP * 4);
    float*    bG   = (float*)alloc((size_t)3 * DP * 4);
    float*    bL   = (float*)alloc((size_t)3 * DP * 4);
    float*    b3   = (float*)alloc((size_t)DP * 4);
    int*      cnt    = (int*)alloc((size_t)(N + 1) * 4);
    int*      offp   = (int*)alloc((size_t)(N + 1) * 4);
    int*      cursor = (int*)alloc((size_t)N * 4);
    int*      bsum   = (int*)alloc((size_t)256 * 4);
    int*      csr    = (int*)alloc((size_t)E * 4);
    float*    sums   = (float*)alloc((size_t)(G * DD + G) * 4);
    float*    cnts   = sums + G * DD;

    const int* srcp = ei;
    const int* dstp = ei + E;
    const int nb = (N + 255) / 256;
    const dim3 blk(256);
    const int rowBlocks = (N + 127) / 128;   // 391
    const int rowBlocksPad = ((rowBlocks + 7) / 8) * 8;  // 392

    // ---- prep (all weight conversions, one launch) ----
    const int prepTotal = 3 * SZ * 3 + 128 * 64 + DP * 128 + 3 * DP * 3 + DP;
    prep<<<dim3((prepTotal + 255) / 256), blk, 0, stream>>>(
        pW2, pW3, pb3, hW, hb, fW, gW, gb, lW, lb,
        WU, WG, WL, W2, W3e, bU, bG, bL, b3);

    // ---- CSR build ----
    hipMemsetAsync(cnt, 0, (size_t)(N + 1) * 4, stream);
    hist_kernel<<<dim3((E + 255) / 256), blk, 0, stream>>>(dstp, cnt, E);
    scan1<<<dim3(nb), blk, 0, stream>>>(cnt, bsum, N);
    scan2<<<dim3(1), blk, 0, stream>>>(bsum, nb);
    scan3<<<dim3(nb), blk, 0, stream>>>(cnt, bsum, offp, cursor, N);
    scatter_kernel<<<dim3((E + 255) / 256), blk, 0, stream>>>(srcp, dstp, cursor, csr, E);

    // ---- embed MLP ----
    embed1<<<dim3((N * 64 + 255) / 256), blk, 0, stream>>>(x, pW1, pb1, h1, N);
    gemm_mfma<4, 1, 1, 0, 0><<<dim3(1, rowBlocks), dim3(512), 0, stream>>>(
        h1, 64, N, 64, W2, pb2, nullptr, nullptr, nullptr, 128, h2, 128);
    gemm_mfma<5, 1, 0, 0, 0><<<dim3(2, rowBlocksPad), dim3(512), 0, stream>>>(
        h2, 128, N, 128, W3e, b3, nullptr, nullptr, nullptr, DD, h, DP);

    // ---- 3 PointGNNConv layers ----
    for (int i = 0; i < 3; ++i) {
        const float* fWi = fW + (size_t)i * 90900;
        const float* fbi = fb + (size_t)i * DD;

        // u = h @ fWh + x @ fWp ; cols 300-302 = delta = h @ hW + hb (fused)
        gemm_mfma<5, 1, 0, 0, 1><<<dim3(2, rowBlocksPad), dim3(512), 0, stream>>>(
            h, DP, N, DP, WU + (size_t)i * SZ, bU + (size_t)i * DP,
            nullptr, x, fWi, DD, u, DP);

        // agg = segment_max(u[src], dst) + fb + (delta-pos)@fWp
        segmax<<<dim3((N + 3) / 4), blk, 0, stream>>>(u, offp, csr, x, fWi, fbi, agg, N);

        // t = relu(agg @ gW + gb + h) -> u buffer
        gemm_mfma<5, 1, 1, 1, 0><<<dim3(2, rowBlocksPad), dim3(512), 0, stream>>>(
            agg, DP, N, DP, WG + (size_t)i * SZ, bG + (size_t)i * DP,
            h, nullptr, nullptr, DD, u, DP);

        // h = t @ lW + lb
        gemm_mfma<5, 1, 0, 0, 0><<<dim3(2, rowBlocksPad), dim3(512), 0, stream>>>(
            u, DP, N, DP, WL + (size_t)i * SZ, bL + (size_t)i * DP,
            nullptr, nullptr, nullptr, DD, h, DP);
    }

    // ---- global mean pool + head ----
    hipMemsetAsync(sums, 0, (size_t)(G * DD + G) * 4, stream);
    pool_kernel<<<dim3((N + 127) / 128), dim3(320), 0, stream>>>(h, batch, sums, cnts, N, 128);
    head_kernel<<<dim3(1), dim3(256), 0, stream>>>(sums, cnts, dW, db, (float*)d_out);
}